// Round 10
// baseline (435.636 us; speedup 1.0000x reference)
//
#include <hip/hip_runtime.h>
#include <math.h>

#define IN_C 128
#define OUT_C 128
#define BD 64  // BASES*HEAD_D

// ---------------- edge counting ----------------
__global__ void k_count(const int* __restrict__ col, int E, int* __restrict__ cnt) {
    int e = blockIdx.x * blockDim.x + threadIdx.x;
    if (e < E) atomicAdd(&cnt[col[e]], 1);
}

// ---------------- exclusive scan (single block, 1024 threads) ----------------
__global__ void k_scan(const int* __restrict__ cnt, int* __restrict__ start, int n) {
    __shared__ int part[1024];
    int t = threadIdx.x;
    int C = (n + 1023) >> 10;
    int lo = t * C, hi = min(n, lo + C);
    int s = 0;
    for (int i = lo; i < hi; ++i) s += cnt[i];
    part[t] = s;
    __syncthreads();
    for (int off = 1; off < 1024; off <<= 1) {
        int v = (t >= off) ? part[t - off] : 0;
        __syncthreads();
        part[t] += v;
        __syncthreads();
    }
    int run = (t == 0) ? 0 : part[t - 1];
    for (int i = lo; i < hi; ++i) { start[i] = run; run += cnt[i]; }
}

// ---------------- bucket edges by destination ----------------
__global__ void k_bucket(const int* __restrict__ row, const int* __restrict__ col,
                         int E, const int* __restrict__ start, int* __restrict__ pos,
                         int* __restrict__ esrc) {
    int e = blockIdx.x * blockDim.x + threadIdx.x;
    if (e < E) {
        int c = col[e];
        int p = atomicAdd(&pos[c], 1);
        esrc[start[c] + p] = row[e];
    }
}

// ---------------- bases = x @ bases_W  (+ dinv) ----------------
__global__ void k_bases(const float* __restrict__ x, const float* __restrict__ Wb,
                        const int* __restrict__ cnt, float* __restrict__ bases,
                        float* __restrict__ dinv, int Nn) {
    __shared__ float xs[4][IN_C];
    int t = threadIdx.x;
    int nb = blockIdx.x * 4;
    for (int i = t; i < 4 * IN_C; i += 256) {
        int r = i >> 7, c = i & 127;
        int n = nb + r;
        xs[r][c] = (n < Nn) ? x[(size_t)n * IN_C + c] : 0.f;
    }
    __syncthreads();
    int nl = t >> 6, dout = t & 63;
    int n = nb + nl;
    if (n >= Nn) return;
    int b = dout >> 4, d = dout & 15;
    const float* wp = Wb + b * (IN_C * 16) + d;
    float acc = 0.f;
#pragma unroll 8
    for (int c = 0; c < IN_C; ++c) acc = fmaf(xs[nl][c], wp[c * 16], acc);
    bases[(size_t)n * BD + dout] = acc;
    if (dout == 0) dinv[n] = rsqrtf((float)cnt[n] + 1.0f);
}

// ---- fused: comb-weight matvec + softmax + aggregation + combine (1 wave/node) ----
__global__ void k_fused(const float* __restrict__ x, const float* __restrict__ bases,
                        const float* __restrict__ dinv, const int* __restrict__ cnt,
                        const int* __restrict__ start, const int* __restrict__ esrc,
                        const float* __restrict__ Wc, const float* __restrict__ bc,
                        const float* __restrict__ bias, float* __restrict__ out, int Nn) {
    __shared__ float xs[4][IN_C];
    __shared__ float wsh[4][128];
    __shared__ float agg[4][4][BD];
    int t = threadIdx.x;
    int wv = t >> 6, lane = t & 63;
    int node = (blockIdx.x << 2) + wv;  // 4 nodes per 256-thread block
    bool valid = node < Nn;

    // stage x row (wave-private region)
    const float* xr = x + (size_t)node * IN_C;
    xs[wv][lane]      = valid ? xr[lane] : 0.f;
    xs[wv][lane + 64] = valid ? xr[lane + 64] : 0.f;
    __syncthreads();

    // logits for output columns o=lane and o=lane+64
    float l0 = bc[lane], l1 = bc[lane + 64];
#pragma unroll 4
    for (int c = 0; c < IN_C; ++c) {
        float xc = xs[wv][c];
        l0 = fmaf(xc, Wc[(size_t)c * 128 + lane], l0);
        l1 = fmaf(xc, Wc[(size_t)c * 128 + lane + 64], l1);
    }
    // softmax within each 16-lane group (one head per group), both halves
    float m0 = l0, m1 = l1;
#pragma unroll
    for (int m = 1; m < 16; m <<= 1) {
        m0 = fmaxf(m0, __shfl_xor(m0, m, 64));
        m1 = fmaxf(m1, __shfl_xor(m1, m, 64));
    }
    float e0 = __expf(l0 - m0), e1 = __expf(l1 - m1);
    float s0 = e0, s1 = e1;
#pragma unroll
    for (int m = 1; m < 16; m <<= 1) {
        s0 += __shfl_xor(s0, m, 64);
        s1 += __shfl_xor(s1, m, 64);
    }
    wsh[wv][lane]      = e0 / s0;
    wsh[wv][lane + 64] = e1 / s1;

    // aggregation over incoming edges
    float s = 0.f, ss = 0.f, mx = -INFINITY, sy = 0.f;
    int c = 0;
    if (valid) {
        c = cnt[node];
        int st = start[node];
        for (int j0 = 0; j0 < c; j0 += 64) {
            int nj = min(64, c - j0);
            int src_l = 0;
            float dv_l = 0.f;
            if (lane < nj) {
                src_l = esrc[st + j0 + lane];
                dv_l = dinv[src_l];
            }
#pragma unroll 4
            for (int j = 0; j < nj; ++j) {
                int src = __shfl(src_l, j, 64);
                float dv = __shfl(dv_l, j, 64);
                float m = bases[(size_t)src * BD + lane];
                s += m;
                ss = fmaf(m, m, ss);
                mx = fmaxf(mx, m);
                sy = fmaf(dv, m, sy);
            }
        }
        float dn = dinv[node];
        float bself = bases[(size_t)node * BD + lane];
        agg[wv][0][lane] = fmaf(dn * dn, bself, dn * sy);  // symadd (self-loop analytic)
        float cc = fmaxf((float)c, 1.0f);
        float mean = s / cc;
        agg[wv][1][lane] = mean;
        agg[wv][2][lane] = (c > 0) ? mx : 0.0f;
        float var = ss / cc - mean * mean;
        agg[wv][3][lane] = sqrtf(fmaxf(var, 0.f) + 1e-5f);
    }
    __syncthreads();

    // combine: z[o] = bias[o] + sum_{b,a} w[h,b,a] * agg[a][b*16+d]
    if (valid) {
        float* outp = out + (size_t)node * OUT_C;
#pragma unroll
        for (int half = 0; half < 2; ++half) {
            int o = lane + (half << 6);
            int h = o >> 4, d = o & 15;
            float z = bias[o];
#pragma unroll
            for (int b = 0; b < 4; ++b) {
                const float* wp = &wsh[wv][h * 16 + b * 4];
                z = fmaf(wp[0], agg[wv][0][b * 16 + d], z);
                z = fmaf(wp[1], agg[wv][1][b * 16 + d], z);
                z = fmaf(wp[2], agg[wv][2][b * 16 + d], z);
                z = fmaf(wp[3], agg[wv][3][b * 16 + d], z);
            }
            outp[o] = z;
        }
    }
}

extern "C" void kernel_launch(void* const* d_in, const int* in_sizes, int n_in,
                              void* d_out, int out_size, void* d_ws, size_t ws_size,
                              hipStream_t stream) {
    const float* x       = (const float*)d_in[0];
    const int* ei        = (const int*)d_in[1];  // harness passes integer inputs as int32
    const float* bases_W = (const float*)d_in[2];
    const float* comb_W  = (const float*)d_in[3];
    const float* comb_b  = (const float*)d_in[4];
    const float* bias    = (const float*)d_in[5];
    float* out = (float*)d_out;

    int N = in_sizes[0] / IN_C;
    int E = in_sizes[1] / 2;
    const int* row = ei;      // messages flow row -> col
    const int* col = ei + E;

    char* ws = (char*)d_ws;
    size_t off = 0;
    auto alloc = [&](size_t bytes) {
        void* p = ws + off;
        off = (off + bytes + 255) & ~(size_t)255;
        return p;
    };
    int*   cnt   = (int*)alloc((size_t)N * 4);
    int*   start = (int*)alloc((size_t)N * 4);
    int*   pos   = (int*)alloc((size_t)N * 4);
    float* dinv  = (float*)alloc((size_t)N * 4);
    int*   esrc  = (int*)alloc((size_t)E * 4);
    float* bases = (float*)alloc((size_t)N * BD * 4);

    // Guard: fail cleanly (absmax mismatch) instead of faulting if ws too small.
    if (off > ws_size) return;

    hipMemsetAsync(cnt, 0, (size_t)N * 4, stream);
    hipMemsetAsync(pos, 0, (size_t)N * 4, stream);

    int eb = (E + 255) / 256;
    k_count<<<eb, 256, 0, stream>>>(col, E, cnt);
    k_scan<<<1, 1024, 0, stream>>>(cnt, start, N);
    k_bucket<<<eb, 256, 0, stream>>>(row, col, E, start, pos, esrc);
    k_bases<<<(N + 3) / 4, 256, 0, stream>>>(x, bases_W, cnt, bases, dinv, N);
    k_fused<<<(N + 3) / 4, 256, 0, stream>>>(x, bases, dinv, cnt, start, esrc,
                                             comb_W, comb_b, bias, out, N);
}